// Round 6
// baseline (1252.456 us; speedup 1.0000x reference)
//
#include <hip/hip_runtime.h>
#include <cstdint>
#include <cstddef>

namespace {

constexpr int T = 10;
constexpr int N = 50000;
constexpr int R = 50000;
constexpr int DIN = 128;
constexpr int D = 64;
constexpr int E = 400000;
constexpr int EV4 = E / 4;              // 100000 int4 groups per t

// packed node counter: count in bits [24..31], weight-sum fixed 2^-18 in [0..23]
constexpr float WSCALE = 262144.0f;     // 2^18
constexpr float WINV = 1.0f / 262144.0f;

typedef _Float16 h16;
typedef __attribute__((ext_vector_type(8))) _Float16 f16x8;
typedef __attribute__((ext_vector_type(4))) _Float16 f16x4;
typedef __attribute__((ext_vector_type(4))) float f32x4;

__device__ __forceinline__ unsigned short f16bits(float f) {
  _Float16 h = (_Float16)f;
  unsigned short b;
  __builtin_memcpy(&b, &h, 2);
  return b;
}
__device__ __forceinline__ float upw(unsigned r) {
  unsigned short b = (unsigned short)(r & 0xFFFFu);
  _Float16 h;
  __builtin_memcpy(&h, &b, 2);
  return (float)h;
}

// ---------------------------------------------------------------- prep: weights fp32->f16, zero pu32/tbase
__global__ __launch_bounds__(256) void k_prep(const float* __restrict__ g1w,
                                              const float* __restrict__ g2w,
                                              const float* __restrict__ inw,
                                              const float* __restrict__ outw,
                                              const float* __restrict__ fcw,
                                              h16* __restrict__ Wb,
                                              unsigned* __restrict__ pu32,
                                              int* __restrict__ tbase) {
  int i = blockIdx.x * 256 + threadIdx.x;
  if (i < 32768) {
    const float* src;
    int off;
    if (i < 8192)       { src = g1w;  off = 0; }
    else if (i < 12288) { src = g2w;  off = 8192; }
    else if (i < 24576) { src = inw;  off = 12288; }
    else if (i < 28672) { src = outw; off = 24576; }
    else                { src = fcw;  off = 28672; }
    Wb[i] = (h16)src[i - off];
  }
  if (i < 16) tbase[i] = 0;
  if (i < T * N) pu32[i] = 0u;
}

// ---------------------------------------------------------------- pass 1: per-node packed count/degree (global atomics)
__global__ __launch_bounds__(256) void k_count(const int* __restrict__ ei,
                                               const float* __restrict__ ew,
                                               unsigned* __restrict__ pu32) {
  int t = blockIdx.y;
  int i = blockIdx.x * 256 + threadIdx.x;
  if (i >= EV4) return;
  const int4* dst4 = (const int4*)(ei + (size_t)t * 2 * E + E);
  const float4* ew4 = (const float4*)(ew + (size_t)t * E);
  int4 d = dst4[i];
  float4 w = ew4[i];
  unsigned* put = pu32 + (size_t)t * N;
  atomicAdd(&put[d.x], 0x1000000u + (unsigned)fmaf(w.x, WSCALE, 0.5f));
  atomicAdd(&put[d.y], 0x1000000u + (unsigned)fmaf(w.y, WSCALE, 0.5f));
  atomicAdd(&put[d.z], 0x1000000u + (unsigned)fmaf(w.z, WSCALE, 0.5f));
  atomicAdd(&put[d.w], 0x1000000u + (unsigned)fmaf(w.w, WSCALE, 0.5f));
}

// ---------------------------------------------------------------- pass 2: pu32 -> cnt, dinv, rowptr (block scan + per-t atomic base), cur
__global__ __launch_bounds__(256) void k_hred3(const unsigned* __restrict__ pu32,
                                               int* __restrict__ cnt,
                                               float* __restrict__ dinv,
                                               int* __restrict__ rowptr,
                                               unsigned* __restrict__ cur,
                                               int* __restrict__ tbase) {
  int t = blockIdx.y;
  int n = blockIdx.x * 256 + threadIdx.x;
  int lane = threadIdx.x & 63, wid = threadIdx.x >> 6;
  __shared__ int wsum[4];
  __shared__ int base_s;
  bool ok = (n < N);
  unsigned v = ok ? pu32[(size_t)t * N + n] : 0u;
  unsigned c = v >> 24;
  if (ok) {
    cnt[t * N + n] = (int)c;
    dinv[t * N + n] = rsqrtf(1.0f + (float)(v & 0xFFFFFFu) * WINV);
  }
  int sv = (int)c;
  #pragma unroll
  for (int off = 1; off < 64; off <<= 1) {
    int u = __shfl_up(sv, off, 64);
    if (lane >= off) sv += u;
  }
  if (lane == 63) wsum[wid] = sv;
  __syncthreads();
  int wadd = 0;
  #pragma unroll
  for (int w = 0; w < 4; ++w) if (w < wid) wadd += wsum[w];
  if (threadIdx.x == 255) base_s = atomicAdd(&tbase[t], wadd + sv);
  __syncthreads();
  if (ok) {
    int run = base_s + wadd + sv - (int)c;
    rowptr[t * N + n] = run;
    cur[t * N + n] = (unsigned)run;
  }
}

// ---------------------------------------------------------------- pass 3: place packed (src<<16 | f16(ew)) via global cursors
__global__ __launch_bounds__(256) void k_fill3(const int* __restrict__ ei,
                                               const float* __restrict__ ew,
                                               unsigned* __restrict__ cur,
                                               unsigned* __restrict__ pk) {
  int t = blockIdx.y;
  int i = blockIdx.x * 256 + threadIdx.x;
  if (i >= EV4) return;
  const int4* src4 = (const int4*)(ei + (size_t)t * 2 * E);
  const int4* dst4 = (const int4*)(ei + (size_t)t * 2 * E + E);
  const float4* ew4 = (const float4*)(ew + (size_t)t * E);
  int4 sv = src4[i];
  int4 d = dst4[i];
  float4 w = ew4[i];
  unsigned* curt = cur + (size_t)t * N;
  unsigned* pkt = pk + (size_t)t * E;
  unsigned p0 = atomicAdd(&curt[d.x], 1u);
  pkt[p0] = ((unsigned)sv.x << 16) | f16bits(w.x);
  unsigned p1 = atomicAdd(&curt[d.y], 1u);
  pkt[p1] = ((unsigned)sv.y << 16) | f16bits(w.y);
  unsigned p2 = atomicAdd(&curt[d.z], 1u);
  pkt[p2] = ((unsigned)sv.z << 16) | f16bits(w.z);
  unsigned p3 = atomicAdd(&curt[d.w], 1u);
  pkt[p3] = ((unsigned)sv.w << 16) | f16bits(w.w);
}

// ---------------------------------------------------------------- MFMA GEMM: out[m][j] = sum_k W[j][k] * B[m][k]
// C/D layout (16x16x32): col = lane&15 -> m; row = quad*4+reg -> j.
// MODE 0: plain f16 out.  MODE 2: row-scale by biasp[m] (dinv).
template <int K, int NT, bool F16B, int MODE>
__global__ __launch_bounds__(256) void k_mm(const h16* __restrict__ Wb,
                                            const void* __restrict__ Bv,
                                            const float* __restrict__ biasp,
                                            h16* __restrict__ out,
                                            int Mwaves) {
  int wv = threadIdx.x >> 6, lane = threadIdx.x & 63;
  int wave = blockIdx.x * 4 + wv;
  if (wave >= Mwaves) return;
  int m0 = wave * 16;
  int half = lane & 15, quad = lane >> 4;
  constexpr int KS = K / 32;
  int m = m0 + half;
  float ds = 1.0f;
  if (MODE == 2) ds = biasp[m];
  f16x8 bfrag[KS];
  if (F16B) {
    const h16* Bp = (const h16*)Bv + (size_t)m * K + quad * 8;
    #pragma unroll
    for (int ks = 0; ks < KS; ++ks) bfrag[ks] = *(const f16x8*)(Bp + ks * 32);
  } else {
    const float* Bp = (const float*)Bv + (size_t)m * K + quad * 8;
    #pragma unroll
    for (int ks = 0; ks < KS; ++ks) {
      float4 f0 = *(const float4*)(Bp + ks * 32);
      float4 f1 = *(const float4*)(Bp + ks * 32 + 4);
      f16x8 b;
      b[0] = (h16)f0.x; b[1] = (h16)f0.y; b[2] = (h16)f0.z; b[3] = (h16)f0.w;
      b[4] = (h16)f1.x; b[5] = (h16)f1.y; b[6] = (h16)f1.z; b[7] = (h16)f1.w;
      bfrag[ks] = b;
    }
  }
  #pragma unroll
  for (int jt = 0; jt < NT; ++jt) {
    f32x4 acc = {0.f, 0.f, 0.f, 0.f};
    const h16* Wp = Wb + (size_t)(jt * 16 + half) * K + quad * 8;
    #pragma unroll
    for (int ks = 0; ks < KS; ++ks) {
      f16x8 afrag = *(const f16x8*)(Wp + ks * 32);
      acc = __builtin_amdgcn_mfma_f32_16x16x32_f16(afrag, bfrag[ks], acc, 0, 0, 0);
    }
    int j = jt * 16 + quad * 4;
    if (MODE == 2) {
      acc[0] *= ds; acc[1] *= ds; acc[2] *= ds; acc[3] *= ds;
    }
    f16x4 o;
    o[0] = (h16)acc[0]; o[1] = (h16)acc[1]; o[2] = (h16)acc[2]; o[3] = (h16)acc[3];
    *(f16x4*)(out + (size_t)m * (NT * 16) + j) = o;
  }
}

// ---------------------------------------------------------------- GCN aggregation (gather over CSR)
// 2 nodes per wave, 4 groups x 8 lanes per node; each lane covers 8 features
// (16B f16 loads). Quad-unrolled edge loop; packed u32 records.
template <bool SCATTER>
__global__ __launch_bounds__(256) void k_gather(
    const h16* __restrict__ hw, const unsigned* __restrict__ pk,
    const float* __restrict__ dinv, const int* __restrict__ rowptr,
    const int* __restrict__ cnt, const float* __restrict__ bias,
    const int* __restrict__ gidx, h16* __restrict__ outp) {
  __shared__ __align__(16) float red[4][8][68];  // [wave][nd*4+grp][feat pad+4]
  int wv = threadIdx.x >> 6, lane = threadIdx.x & 63;
  int t = blockIdx.y;
  int nd = lane >> 5;            // which of the 2 nodes
  int grp = (lane >> 3) & 3;     // 4 edge-groups per node
  int sub = lane & 7;            // 8 feature-lanes per group
  int n = blockIdx.x * 8 + wv * 2 + nd;
  const h16* hwt = hw + (size_t)t * N * D;
  const unsigned* pkt = pk + (size_t)t * E;
  int start = rowptr[t * N + n];
  int m = cnt[t * N + n];
  // hoist independent epilogue loads (lane = feature for node nA/nB)
  int nA = blockIdx.x * 8 + wv * 2;
  int nB = nA + 1;
  float selfA = (float)hwt[(size_t)nA * D + lane];
  float selfB = (float)hwt[(size_t)nB * D + lane];
  float dnA = dinv[t * N + nA];
  float dnB = dinv[t * N + nB];
  float bi = bias[lane];
  f32x4 accL = {0.f, 0.f, 0.f, 0.f};
  f32x4 accH = {0.f, 0.f, 0.f, 0.f};
  int e = grp;
  for (; e + 12 < m; e += 16) {
    unsigned r0 = pkt[start + e];
    unsigned r1 = pkt[start + e + 4];
    unsigned r2 = pkt[start + e + 8];
    unsigned r3 = pkt[start + e + 12];
    float w0 = upw(r0);
    float w1 = upw(r1);
    float w2 = upw(r2);
    float w3 = upw(r3);
    f16x8 h0 = *(const f16x8*)(hwt + (size_t)(r0 >> 16) * D + sub * 8);
    f16x8 h1 = *(const f16x8*)(hwt + (size_t)(r1 >> 16) * D + sub * 8);
    f16x8 h2 = *(const f16x8*)(hwt + (size_t)(r2 >> 16) * D + sub * 8);
    f16x8 h3 = *(const f16x8*)(hwt + (size_t)(r3 >> 16) * D + sub * 8);
    #pragma unroll
    for (int j = 0; j < 4; ++j) {
      accL[j] = fmaf(w0, (float)h0[j], accL[j]);
      accH[j] = fmaf(w0, (float)h0[j + 4], accH[j]);
    }
    #pragma unroll
    for (int j = 0; j < 4; ++j) {
      accL[j] = fmaf(w1, (float)h1[j], accL[j]);
      accH[j] = fmaf(w1, (float)h1[j + 4], accH[j]);
    }
    #pragma unroll
    for (int j = 0; j < 4; ++j) {
      accL[j] = fmaf(w2, (float)h2[j], accL[j]);
      accH[j] = fmaf(w2, (float)h2[j + 4], accH[j]);
    }
    #pragma unroll
    for (int j = 0; j < 4; ++j) {
      accL[j] = fmaf(w3, (float)h3[j], accL[j]);
      accH[j] = fmaf(w3, (float)h3[j + 4], accH[j]);
    }
  }
  for (; e + 4 < m; e += 8) {
    unsigned ra = pkt[start + e];
    unsigned rb = pkt[start + e + 4];
    float wa = upw(ra);
    float wb = upw(rb);
    f16x8 ha = *(const f16x8*)(hwt + (size_t)(ra >> 16) * D + sub * 8);
    f16x8 hb = *(const f16x8*)(hwt + (size_t)(rb >> 16) * D + sub * 8);
    #pragma unroll
    for (int j = 0; j < 4; ++j) {
      accL[j] = fmaf(wa, (float)ha[j], accL[j]);
      accH[j] = fmaf(wa, (float)ha[j + 4], accH[j]);
    }
    #pragma unroll
    for (int j = 0; j < 4; ++j) {
      accL[j] = fmaf(wb, (float)hb[j], accL[j]);
      accH[j] = fmaf(wb, (float)hb[j + 4], accH[j]);
    }
  }
  if (e < m) {
    unsigned ra = pkt[start + e];
    float wa = upw(ra);
    f16x8 ha = *(const f16x8*)(hwt + (size_t)(ra >> 16) * D + sub * 8);
    #pragma unroll
    for (int j = 0; j < 4; ++j) {
      accL[j] = fmaf(wa, (float)ha[j], accL[j]);
      accH[j] = fmaf(wa, (float)ha[j + 4], accH[j]);
    }
  }
  // wave-synchronous LDS reduce across the 4 groups of each node
  float* rw = &red[wv][nd * 4 + grp][sub * 8];
  *(f32x4*)(rw) = accL;
  *(f32x4*)(rw + 4) = accH;
  __builtin_amdgcn_wave_barrier();
  // epilogue: lane owns feature `lane`, loops over the 2 nodes
  #pragma unroll
  for (int d2 = 0; d2 < 2; ++d2) {
    int nn = nA + d2;
    float s = red[wv][d2 * 4 + 0][lane] + red[wv][d2 * 4 + 1][lane] +
              red[wv][d2 * 4 + 2][lane] + red[wv][d2 * 4 + 3][lane];
    float selfv = d2 ? selfB : selfA;
    float dn = d2 ? dnB : dnA;
    float v = fmaxf(fmaf(dn, s + selfv, bi), 0.f);
    size_t ro;
    if (SCATTER) {
      int rr2 = gidx[(size_t)t * R + nn];
      ro = ((size_t)rr2 * T + t) * D + lane;
    } else {
      ro = ((size_t)t * N + nn) * D + lane;
    }
    outp[ro] = (h16)v;
  }
}

// ---------------------------------------------------------------- fused attention tail
// One block = 16 r's (160 te rows). qkv MFMA -> LDS, attention, out_proj MFMA,
// LN1, fc MFMA, LN2 -> global f32 out. kv never touches global memory.
constexpr int KVP = 132;   // kv row pad (f16) -> 264 B rows, 2-way bank spread
constexpr int P72 = 72;    // 16-row tile pad  -> 144 B rows, 16B-aligned

__global__ __launch_bounds__(256) void k_tail(
    const h16* __restrict__ te,      // [R*T][64] f16
    const h16* __restrict__ WIb,     // in_proj [192][64]
    const float* __restrict__ inB,
    const h16* __restrict__ WOb,     // out_proj [64][64]
    const float* __restrict__ outB,
    const h16* __restrict__ WFb,     // fc [64][64]
    const float* __restrict__ fcB,
    const float* __restrict__ w1,
    const float* __restrict__ w2,
    const float* __restrict__ w3,
    const float* __restrict__ w4,
    const float* __restrict__ g1, const float* __restrict__ b1,
    const float* __restrict__ g2, const float* __restrict__ b2,
    float* __restrict__ outp) {
  __shared__ __align__(16) h16 kvl[160][KVP];   // k cols 0..63, v cols 64..127
  __shared__ __align__(16) h16 ql[16][P72];
  __shared__ __align__(16) h16 aol[16][P72];
  __shared__ __align__(16) h16 tbuf[16][P72];   // proj, then o2
  __shared__ __align__(16) h16 fbuf[16][P72];   // finb
  __shared__ __align__(16) float pf[16][64];    // fin f32

  int wv = threadIdx.x >> 6, lane = threadIdx.x & 63;
  int half = lane & 15, quad = lane >> 4;
  int g0 = blockIdx.x * 160;  // first global te row (r0*T)

  // ---- step 1: qkv = te @ in_w^T (+b) into LDS
  for (int tt = wv; tt < 10; tt += 4) {
    int lr = tt * 16 + half;  // local row 0..159
    const h16* Bp = te + (size_t)(g0 + lr) * 64 + quad * 8;
    f16x8 b0 = *(const f16x8*)(Bp);
    f16x8 b1f = *(const f16x8*)(Bp + 32);
    int rloc = lr / 10;
    bool isq = (lr - rloc * 10) == 9;
    #pragma unroll
    for (int jt = 0; jt < 12; ++jt) {
      f32x4 acc = {0.f, 0.f, 0.f, 0.f};
      const h16* Wp = WIb + (size_t)(jt * 16 + half) * 64 + quad * 8;
      acc = __builtin_amdgcn_mfma_f32_16x16x32_f16(*(const f16x8*)(Wp), b0, acc, 0, 0, 0);
      acc = __builtin_amdgcn_mfma_f32_16x16x32_f16(*(const f16x8*)(Wp + 32), b1f, acc, 0, 0, 0);
      int j = jt * 16 + quad * 4;
      float4 b4 = *(const float4*)(inB + j);
      f16x4 o;
      o[0] = (h16)(acc[0] + b4.x); o[1] = (h16)(acc[1] + b4.y);
      o[2] = (h16)(acc[2] + b4.z); o[3] = (h16)(acc[3] + b4.w);
      if (jt < 4) {
        if (isq) *(f16x4*)(&ql[rloc][j]) = o;
      } else {
        *(f16x4*)(&kvl[lr][j - 64]) = o;
      }
    }
  }
  __syncthreads();

  // ---- step 2: attention (one wave per r, 4 rounds); lane = feature
  #pragma unroll
  for (int i = 0; i < 4; ++i) {
    int rl = wv * 4 + i;
    float qv = (float)ql[rl][lane];
    float sc[T], vv[T];
    #pragma unroll
    for (int s = 0; s < T; ++s) {
      float kk = (float)kvl[rl * 10 + s][lane];
      vv[s] = (float)kvl[rl * 10 + s][64 + lane];
      float p = qv * kk;
      p += __shfl_xor(p, 8, 16);
      p += __shfl_xor(p, 4, 16);
      p += __shfl_xor(p, 2, 16);
      p += __shfl_xor(p, 1, 16);
      sc[s] = p * 0.25f;  // 1/sqrt(16)
    }
    float mx = sc[0];
    #pragma unroll
    for (int s = 1; s < T; ++s) mx = fmaxf(mx, sc[s]);
    float ssum = 0.f;
    #pragma unroll
    for (int s = 0; s < T; ++s) { sc[s] = expf(sc[s] - mx); ssum += sc[s]; }
    float rinv = 1.0f / ssum;
    float aov = 0.f;
    #pragma unroll
    for (int s = 0; s < T; ++s) aov = fmaf(sc[s] * rinv, vv[s], aov);
    aol[rl][lane] = (h16)aov;
  }
  __syncthreads();

  // ---- step 3: proj = ao @ out_w^T + outB (one 16x64 tile; wave wv owns jt=wv)
  {
    const h16* Bp = &aol[half][quad * 8];
    f16x8 b0 = *(const f16x8*)(Bp);
    f16x8 b1f = *(const f16x8*)(Bp + 32);
    f32x4 acc = {0.f, 0.f, 0.f, 0.f};
    const h16* Wp = WOb + (size_t)(wv * 16 + half) * 64 + quad * 8;
    acc = __builtin_amdgcn_mfma_f32_16x16x32_f16(*(const f16x8*)(Wp), b0, acc, 0, 0, 0);
    acc = __builtin_amdgcn_mfma_f32_16x16x32_f16(*(const f16x8*)(Wp + 32), b1f, acc, 0, 0, 0);
    int j = wv * 16 + quad * 4;
    float4 b4 = *(const float4*)(outB + j);
    f16x4 o;
    o[0] = (h16)(acc[0] + b4.x); o[1] = (h16)(acc[1] + b4.y);
    o[2] = (h16)(acc[2] + b4.z); o[3] = (h16)(acc[3] + b4.w);
    *(f16x4*)(&tbuf[half][j]) = o;
  }
  __syncthreads();

  // ---- step 4: LN1 per r (one wave per r, 4 rounds)
  {
    float w1l = w1[(T - 1) * 64 + lane];
    float w2l = w2[(T - 1) * 64 + lane];
    float g1l = g1[lane], b1l = b1[lane];
    #pragma unroll
    for (int i = 0; i < 4; ++i) {
      int rl = wv * 4 + i;
      float t9 = (float)te[(size_t)(g0 + rl * 10 + 9) * 64 + lane];
      float pr = (float)tbuf[rl][lane];
      float pre = w1l * t9 + w2l * pr;
      float s1 = pre;
      #pragma unroll
      for (int off = 32; off >= 1; off >>= 1) s1 += __shfl_xor(s1, off, 64);
      float mu = s1 * (1.0f / 64.0f);
      float dv = pre - mu;
      float s2 = dv * dv;
      #pragma unroll
      for (int off = 32; off >= 1; off >>= 1) s2 += __shfl_xor(s2, off, 64);
      float rstd = 1.0f / sqrtf(s2 * (1.0f / 64.0f) + 1e-5f);
      float fin = dv * rstd * g1l + b1l;
      pf[rl][lane] = fin;
      fbuf[rl][lane] = (h16)fin;
    }
  }
  __syncthreads();

  // ---- step 5: o2 = fin @ fc_w^T + fcB
  {
    const h16* Bp = &fbuf[half][quad * 8];
    f16x8 b0 = *(const f16x8*)(Bp);
    f16x8 b1f = *(const f16x8*)(Bp + 32);
    f32x4 acc = {0.f, 0.f, 0.f, 0.f};
    const h16* Wp = WFb + (size_t)(wv * 16 + half) * 64 + quad * 8;
    acc = __builtin_amdgcn_mfma_f32_16x16x32_f16(*(const f16x8*)(Wp), b0, acc, 0, 0, 0);
    acc = __builtin_amdgcn_mfma_f32_16x16x32_f16(*(const f16x8*)(Wp + 32), b1f, acc, 0, 0, 0);
    int j = wv * 16 + quad * 4;
    float4 b4 = *(const float4*)(fcB + j);
    f16x4 o;
    o[0] = (h16)(acc[0] + b4.x); o[1] = (h16)(acc[1] + b4.y);
    o[2] = (h16)(acc[2] + b4.z); o[3] = (h16)(acc[3] + b4.w);
    *(f16x4*)(&tbuf[half][j]) = o;
  }
  __syncthreads();

  // ---- step 6: LN2 per r -> global out
  {
    float w3l = w3[lane], w4l = w4[lane];
    float g2l = g2[lane], b2l = b2[lane];
    #pragma unroll
    for (int i = 0; i < 4; ++i) {
      int rl = wv * 4 + i;
      float fin = pf[rl][lane];
      float oo = (float)tbuf[rl][lane];
      float pre = w3l * fin + w4l * oo;
      float s1 = pre;
      #pragma unroll
      for (int off = 32; off >= 1; off >>= 1) s1 += __shfl_xor(s1, off, 64);
      float mu = s1 * (1.0f / 64.0f);
      float dv = pre - mu;
      float s2 = dv * dv;
      #pragma unroll
      for (int off = 32; off >= 1; off >>= 1) s2 += __shfl_xor(s2, off, 64);
      float rstd = 1.0f / sqrtf(s2 * (1.0f / 64.0f) + 1e-5f);
      outp[(size_t)(blockIdx.x * 16 + rl) * 64 + lane] = dv * rstd * g2l + b2l;
    }
  }
}

}  // namespace

extern "C" void kernel_launch(void* const* d_in, const int* in_sizes, int n_in,
                              void* d_out, int out_size, void* d_ws, size_t ws_size,
                              hipStream_t stream) {
  const float* x      = (const float*)d_in[0];
  const int*   ei     = (const int*)d_in[1];
  const float* ew     = (const float*)d_in[2];
  const int*   gidx   = (const int*)d_in[3];
  const float* gcn1_w = (const float*)d_in[4];
  const float* gcn1_b = (const float*)d_in[5];
  const float* gcn2_w = (const float*)d_in[6];
  const float* gcn2_b = (const float*)d_in[7];
  const float* in_w   = (const float*)d_in[8];
  const float* in_b   = (const float*)d_in[9];
  const float* out_w  = (const float*)d_in[10];
  const float* out_b  = (const float*)d_in[11];
  const float* w1     = (const float*)d_in[12];
  const float* w2     = (const float*)d_in[13];
  const float* w3     = (const float*)d_in[14];
  const float* w4     = (const float*)d_in[15];
  const float* ln1_g  = (const float*)d_in[16];
  const float* ln1_b  = (const float*)d_in[17];
  const float* ln2_g  = (const float*)d_in[18];
  const float* ln2_b  = (const float*)d_in[19];
  const float* fc_w   = (const float*)d_in[20];
  const float* fc_b   = (const float*)d_in[21];
  float* outp = (float*)d_out;

  char* ws = (char*)d_ws;
  size_t off = 0;
  auto alloc = [&](size_t bytes) {
    void* p = ws + off;
    off += (bytes + 255) & ~(size_t)255;
    return p;
  };
  // persistent region
  h16* h1te = (h16*)alloc(sizeof(h16) * (size_t)T * N * D);  // h1 / time_embeds
  h16* Wb   = (h16*)alloc(sizeof(h16) * 32768);
  int* tbase = (int*)alloc(sizeof(int) * 16);
  // graph-prep buffers
  float* dinv   = (float*)alloc(sizeof(float) * T * N);
  int*   cnt    = (int*)alloc(sizeof(int) * T * N);
  int*   rowptr = (int*)alloc(sizeof(int) * T * N);
  unsigned* pk  = (unsigned*)alloc(sizeof(unsigned) * (size_t)T * E);  // 16 MB
  // union: pu32/cur (dead after k_fill3) aliased by hw (first written at GCN1 k_mm)
  size_t u_base = off;
  unsigned* pu32 = (unsigned*)alloc(sizeof(unsigned) * T * N);
  unsigned* cur  = (unsigned*)alloc(sizeof(unsigned) * T * N);
  h16* hw = (h16*)(ws + u_base);
  size_t hw_end = u_base + sizeof(h16) * (size_t)T * N * D;
  if (hw_end > off) off = hw_end;

  const h16* W1b = Wb;           // gcn1_w  [64][128]
  const h16* W2b = Wb + 8192;    // gcn2_w  [64][64]
  const h16* WIb = Wb + 12288;   // in_w    [192][64]
  const h16* WOb = Wb + 24576;   // out_w   [64][64]
  const h16* WFb = Wb + 28672;   // fc_w    [64][64]

  const int M = T * N;
  const int MW = M / 16;   // 31250

  // prep: weight cvt + zero pu32/tbase
  k_prep<<<(T * N + 255) / 256, 256, 0, stream>>>(gcn1_w, gcn2_w, in_w, out_w, fc_w,
                                                  Wb, pu32, tbase);

  // graph prep — single-pass global-atomic pipeline
  dim3 eg((EV4 + 255) / 256, T);
  k_count<<<eg, 256, 0, stream>>>(ei, ew, pu32);
  dim3 hg((N + 255) / 256, T);
  k_hred3<<<hg, 256, 0, stream>>>(pu32, cnt, dinv, rowptr, cur, tbase);
  k_fill3<<<eg, 256, 0, stream>>>(ei, ew, cur, pk);

  // GCN stage (hw rows pre-scaled by dinv via MODE 2)
  dim3 gg(N / 8, T);
  k_mm<DIN, 4, false, 2><<<(MW + 3) / 4, 256, 0, stream>>>(W1b, x, dinv, hw, MW);
  k_gather<false><<<gg, 256, 0, stream>>>(hw, pk, dinv, rowptr, cnt, gcn1_b, nullptr, h1te);
  k_mm<D, 4, true, 2><<<(MW + 3) / 4, 256, 0, stream>>>(W2b, h1te, dinv, hw, MW);
  k_gather<true><<<gg, 256, 0, stream>>>(hw, pk, dinv, rowptr, cnt, gcn2_b, gidx, h1te);

  // fused attention tail: qkv + attn + out_proj + ln1 + fc + ln2
  k_tail<<<R / 16, 256, 0, stream>>>(h1te, WIb, in_b, WOb, out_b, WFb, fc_b,
                                     w1, w2, w3, w4, ln1_g, ln1_b, ln2_g, ln2_b, outp);
}

// Round 7
// 969.318 us; speedup vs baseline: 1.2921x; 1.2921x over previous
//
#include <hip/hip_runtime.h>
#include <cstdint>
#include <cstddef>

namespace {

constexpr int T = 10;
constexpr int N = 50000;
constexpr int R = 50000;
constexpr int DIN = 128;
constexpr int D = 64;
constexpr int E = 400000;

// LDS-binned edge-prep geometry
constexpr int BINS = 16384;             // bins per range (64 KB packed LDS)
constexpr int NR = 4;                   // ranges: 4*16384 = 65536 >= N
constexpr int SEG = 25;                 // edge segments per t (1000 blocks total)
constexpr int ESEG = E / SEG;           // 16000 edges per segment
constexpr int EV4 = ESEG / 4;           // 4000 int4 groups per segment

// hist packing: count in bits [24..31], weight-sum fixed-point 2^-18 in bits [0..23]
constexpr float WSCALE = 262144.0f;     // 2^18
constexpr float WINV = 1.0f / 262144.0f;

typedef _Float16 h16;
typedef __attribute__((ext_vector_type(8))) _Float16 f16x8;
typedef __attribute__((ext_vector_type(4))) _Float16 f16x4;
typedef __attribute__((ext_vector_type(4))) float f32x4;

__device__ __forceinline__ unsigned short f16bits(float f) {
  _Float16 h = (_Float16)f;
  unsigned short b;
  __builtin_memcpy(&b, &h, 2);
  return b;
}
__device__ __forceinline__ float upw(unsigned r) {
  unsigned short b = (unsigned short)(r & 0xFFFFu);
  _Float16 h;
  __builtin_memcpy(&h, &b, 2);
  return (float)h;
}

// ---------------------------------------------------------------- pass A: LDS histogram (packed u32)
__global__ __launch_bounds__(256) void k_hist(const int* __restrict__ ei,
                                              const float* __restrict__ ew,
                                              unsigned* __restrict__ pu) {
  __shared__ unsigned h[BINS];  // 64 KB
  int b = blockIdx.x;
  int s = b % SEG;
  int tr = b / SEG;
  int r = tr % NR;
  int t = tr / NR;
  for (int i = threadIdx.x; i < BINS; i += 256) h[i] = 0u;
  __syncthreads();
  int bin0 = r * BINS;
  const int4* dst4 = (const int4*)(ei + (size_t)t * 2 * E + E + s * ESEG);
  const float4* ew4 = (const float4*)(ew + (size_t)t * E + s * ESEG);
  for (int i = threadIdx.x; i < EV4; i += 256) {
    int4 d = dst4[i];
    float4 w = ew4[i];
    unsigned a0 = (unsigned)(d.x - bin0);
    unsigned a1 = (unsigned)(d.y - bin0);
    unsigned a2 = (unsigned)(d.z - bin0);
    unsigned a3 = (unsigned)(d.w - bin0);
    if (a0 < (unsigned)BINS) atomicAdd(&h[a0], 0x1000000u + (unsigned)fmaf(w.x, WSCALE, 0.5f));
    if (a1 < (unsigned)BINS) atomicAdd(&h[a1], 0x1000000u + (unsigned)fmaf(w.y, WSCALE, 0.5f));
    if (a2 < (unsigned)BINS) atomicAdd(&h[a2], 0x1000000u + (unsigned)fmaf(w.z, WSCALE, 0.5f));
    if (a3 < (unsigned)BINS) atomicAdd(&h[a3], 0x1000000u + (unsigned)fmaf(w.w, WSCALE, 0.5f));
  }
  __syncthreads();
  size_t base = (size_t)b * BINS;
  for (int i = threadIdx.x; i < BINS; i += 256) pu[base + i] = h[i];
}

// ---------------------------------------------------------------- pass B (fused): partials -> cnt, dinv, rowptr (atomic base), seg cursors
__global__ __launch_bounds__(256) void k_hreduce2(unsigned* __restrict__ pu,
                                                  int* __restrict__ cnt,
                                                  float* __restrict__ dinv,
                                                  int* __restrict__ rowptr,
                                                  int* __restrict__ tbase) {
  int t = blockIdx.y;
  int n = blockIdx.x * 256 + threadIdx.x;
  int lane = threadIdx.x & 63, wid = threadIdx.x >> 6;
  __shared__ int wsum[4];
  __shared__ int base_s;
  unsigned cs[SEG];
  unsigned c = 0, wacc = 0;
  bool ok = (n < N);
  int r = 0, rel = 0;
  if (ok) {
    r = n / BINS; rel = n - r * BINS;
    #pragma unroll
    for (int s = 0; s < SEG; ++s) {
      unsigned v = pu[((size_t)((t * NR + r) * SEG + s)) * BINS + rel];
      cs[s] = v >> 24;
      c += cs[s];
      wacc += v & 0xFFFFFFu;
    }
    cnt[t * N + n] = (int)c;
    dinv[t * N + n] = rsqrtf(1.0f + (float)wacc * WINV);  // deg = 1 (self) + sum(ew)
  }
  // block exclusive scan of c
  int sv = (int)c;
  #pragma unroll
  for (int off = 1; off < 64; off <<= 1) {
    int u = __shfl_up(sv, off, 64);
    if (lane >= off) sv += u;
  }
  if (lane == 63) wsum[wid] = sv;
  __syncthreads();
  int wadd = 0;
  #pragma unroll
  for (int w = 0; w < 4; ++w) if (w < wid) wadd += wsum[w];
  if (threadIdx.x == 255) base_s = atomicAdd(&tbase[t], wadd + sv);
  __syncthreads();
  if (ok) {
    unsigned run = (unsigned)(base_s + wadd + sv - (int)c);
    rowptr[t * N + n] = (int)run;
    #pragma unroll
    for (int s = 0; s < SEG; ++s) {
      size_t b = ((size_t)((t * NR + r) * SEG + s)) * BINS + rel;
      pu[b] = run;
      run += cs[s];
    }
  }
}

// ---------------------------------------------------------------- pass D: place packed (src<<16 | f16(ew)) via LDS cursors
__global__ __launch_bounds__(256) void k_fill2(const int* __restrict__ ei,
                                               const float* __restrict__ ew,
                                               const unsigned* __restrict__ pu,
                                               unsigned* __restrict__ pk) {
  __shared__ int cur[BINS];  // 64 KB
  int b = blockIdx.x;
  int s = b % SEG;
  int tr = b / SEG;
  int r = tr % NR;
  int t = tr / NR;
  size_t pbase = (size_t)b * BINS;
  for (int i = threadIdx.x; i < BINS; i += 256) cur[i] = (int)pu[pbase + i];
  __syncthreads();
  int bin0 = r * BINS;
  const int4* src4 = (const int4*)(ei + (size_t)t * 2 * E + s * ESEG);
  const int4* dst4 = (const int4*)(ei + (size_t)t * 2 * E + E + s * ESEG);
  const float4* ew4 = (const float4*)(ew + (size_t)t * E + s * ESEG);
  unsigned* pkt = pk + (size_t)t * E;
  for (int i = threadIdx.x; i < EV4; i += 256) {
    int4 d = dst4[i];
    int4 sv = src4[i];
    float4 w = ew4[i];
    unsigned a0 = (unsigned)(d.x - bin0);
    unsigned a1 = (unsigned)(d.y - bin0);
    unsigned a2 = (unsigned)(d.z - bin0);
    unsigned a3 = (unsigned)(d.w - bin0);
    if (a0 < (unsigned)BINS) {
      int pos = atomicAdd(&cur[a0], 1);
      pkt[pos] = ((unsigned)sv.x << 16) | f16bits(w.x);
    }
    if (a1 < (unsigned)BINS) {
      int pos = atomicAdd(&cur[a1], 1);
      pkt[pos] = ((unsigned)sv.y << 16) | f16bits(w.y);
    }
    if (a2 < (unsigned)BINS) {
      int pos = atomicAdd(&cur[a2], 1);
      pkt[pos] = ((unsigned)sv.z << 16) | f16bits(w.z);
    }
    if (a3 < (unsigned)BINS) {
      int pos = atomicAdd(&cur[a3], 1);
      pkt[pos] = ((unsigned)sv.w << 16) | f16bits(w.w);
    }
  }
}

// ---------------------------------------------------------------- weight prep: fp32 -> fp16 + zero tbase
__global__ __launch_bounds__(256) void k_prep(const float* __restrict__ g1w,
                                              const float* __restrict__ g2w,
                                              const float* __restrict__ inw,
                                              const float* __restrict__ outw,
                                              const float* __restrict__ fcw,
                                              h16* __restrict__ Wb,
                                              int* __restrict__ tbase) {
  int i = blockIdx.x * 256 + threadIdx.x;
  if (i >= 32768) {
    if (i < 32768 + 16) tbase[i - 32768] = 0;
    return;
  }
  const float* src;
  int off;
  if (i < 8192)       { src = g1w;  off = 0; }
  else if (i < 12288) { src = g2w;  off = 8192; }
  else if (i < 24576) { src = inw;  off = 12288; }
  else if (i < 28672) { src = outw; off = 24576; }
  else                { src = fcw;  off = 28672; }
  Wb[i] = (h16)src[i - off];
}

// ---------------------------------------------------------------- MFMA GEMM: out[m][j] = sum_k W[j][k] * B[m][k]
// C/D layout (16x16x32): col = lane&15 -> m; row = quad*4+reg -> j.
// MODE 0: plain f16 out.  MODE 2: row-scale by biasp[m] (dinv).
template <int K, int NT, bool F16B, int MODE>
__global__ __launch_bounds__(256) void k_mm(const h16* __restrict__ Wb,
                                            const void* __restrict__ Bv,
                                            const float* __restrict__ biasp,
                                            h16* __restrict__ out,
                                            int Mwaves) {
  int wv = threadIdx.x >> 6, lane = threadIdx.x & 63;
  int wave = blockIdx.x * 4 + wv;
  if (wave >= Mwaves) return;
  int m0 = wave * 16;
  int half = lane & 15, quad = lane >> 4;
  constexpr int KS = K / 32;
  int m = m0 + half;
  float ds = 1.0f;
  if (MODE == 2) ds = biasp[m];
  f16x8 bfrag[KS];
  if (F16B) {
    const h16* Bp = (const h16*)Bv + (size_t)m * K + quad * 8;
    #pragma unroll
    for (int ks = 0; ks < KS; ++ks) bfrag[ks] = *(const f16x8*)(Bp + ks * 32);
  } else {
    const float* Bp = (const float*)Bv + (size_t)m * K + quad * 8;
    #pragma unroll
    for (int ks = 0; ks < KS; ++ks) {
      float4 f0 = *(const float4*)(Bp + ks * 32);
      float4 f1 = *(const float4*)(Bp + ks * 32 + 4);
      f16x8 b;
      b[0] = (h16)f0.x; b[1] = (h16)f0.y; b[2] = (h16)f0.z; b[3] = (h16)f0.w;
      b[4] = (h16)f1.x; b[5] = (h16)f1.y; b[6] = (h16)f1.z; b[7] = (h16)f1.w;
      bfrag[ks] = b;
    }
  }
  #pragma unroll
  for (int jt = 0; jt < NT; ++jt) {
    f32x4 acc = {0.f, 0.f, 0.f, 0.f};
    const h16* Wp = Wb + (size_t)(jt * 16 + half) * K + quad * 8;
    #pragma unroll
    for (int ks = 0; ks < KS; ++ks) {
      f16x8 afrag = *(const f16x8*)(Wp + ks * 32);
      acc = __builtin_amdgcn_mfma_f32_16x16x32_f16(afrag, bfrag[ks], acc, 0, 0, 0);
    }
    int j = jt * 16 + quad * 4;
    if (MODE == 2) {
      acc[0] *= ds; acc[1] *= ds; acc[2] *= ds; acc[3] *= ds;
    }
    f16x4 o;
    o[0] = (h16)acc[0]; o[1] = (h16)acc[1]; o[2] = (h16)acc[2]; o[3] = (h16)acc[3];
    *(f16x4*)(out + (size_t)m * (NT * 16) + j) = o;
  }
}

// ---------------------------------------------------------------- GCN aggregation (gather over CSR)
// 2 nodes per wave, 4 groups x 8 lanes per node; each lane covers 8 features
// (16B f16 loads). Quad-unrolled edge loop; packed u32 records.
template <bool SCATTER>
__global__ __launch_bounds__(256) void k_gather(
    const h16* __restrict__ hw, const unsigned* __restrict__ pk,
    const float* __restrict__ dinv, const int* __restrict__ rowptr,
    const int* __restrict__ cnt, const float* __restrict__ bias,
    const int* __restrict__ gidx, h16* __restrict__ outp) {
  __shared__ __align__(16) float red[4][8][68];  // [wave][nd*4+grp][feat pad+4]
  int wv = threadIdx.x >> 6, lane = threadIdx.x & 63;
  int t = blockIdx.y;
  int nd = lane >> 5;            // which of the 2 nodes
  int grp = (lane >> 3) & 3;     // 4 edge-groups per node
  int sub = lane & 7;            // 8 feature-lanes per group
  int n = blockIdx.x * 8 + wv * 2 + nd;
  const h16* hwt = hw + (size_t)t * N * D;
  const unsigned* pkt = pk + (size_t)t * E;
  int start = rowptr[t * N + n];
  int m = cnt[t * N + n];
  // hoist independent epilogue loads (lane = feature for node nA/nB)
  int nA = blockIdx.x * 8 + wv * 2;
  int nB = nA + 1;
  float selfA = (float)hwt[(size_t)nA * D + lane];
  float selfB = (float)hwt[(size_t)nB * D + lane];
  float dnA = dinv[t * N + nA];
  float dnB = dinv[t * N + nB];
  float bi = bias[lane];
  f32x4 accL = {0.f, 0.f, 0.f, 0.f};
  f32x4 accH = {0.f, 0.f, 0.f, 0.f};
  int e = grp;
  for (; e + 12 < m; e += 16) {
    unsigned r0 = pkt[start + e];
    unsigned r1 = pkt[start + e + 4];
    unsigned r2 = pkt[start + e + 8];
    unsigned r3 = pkt[start + e + 12];
    float w0 = upw(r0);
    float w1 = upw(r1);
    float w2 = upw(r2);
    float w3 = upw(r3);
    f16x8 h0 = *(const f16x8*)(hwt + (size_t)(r0 >> 16) * D + sub * 8);
    f16x8 h1 = *(const f16x8*)(hwt + (size_t)(r1 >> 16) * D + sub * 8);
    f16x8 h2 = *(const f16x8*)(hwt + (size_t)(r2 >> 16) * D + sub * 8);
    f16x8 h3 = *(const f16x8*)(hwt + (size_t)(r3 >> 16) * D + sub * 8);
    #pragma unroll
    for (int j = 0; j < 4; ++j) {
      accL[j] = fmaf(w0, (float)h0[j], accL[j]);
      accH[j] = fmaf(w0, (float)h0[j + 4], accH[j]);
    }
    #pragma unroll
    for (int j = 0; j < 4; ++j) {
      accL[j] = fmaf(w1, (float)h1[j], accL[j]);
      accH[j] = fmaf(w1, (float)h1[j + 4], accH[j]);
    }
    #pragma unroll
    for (int j = 0; j < 4; ++j) {
      accL[j] = fmaf(w2, (float)h2[j], accL[j]);
      accH[j] = fmaf(w2, (float)h2[j + 4], accH[j]);
    }
    #pragma unroll
    for (int j = 0; j < 4; ++j) {
      accL[j] = fmaf(w3, (float)h3[j], accL[j]);
      accH[j] = fmaf(w3, (float)h3[j + 4], accH[j]);
    }
  }
  for (; e + 4 < m; e += 8) {
    unsigned ra = pkt[start + e];
    unsigned rb = pkt[start + e + 4];
    float wa = upw(ra);
    float wb = upw(rb);
    f16x8 ha = *(const f16x8*)(hwt + (size_t)(ra >> 16) * D + sub * 8);
    f16x8 hb = *(const f16x8*)(hwt + (size_t)(rb >> 16) * D + sub * 8);
    #pragma unroll
    for (int j = 0; j < 4; ++j) {
      accL[j] = fmaf(wa, (float)ha[j], accL[j]);
      accH[j] = fmaf(wa, (float)ha[j + 4], accH[j]);
    }
    #pragma unroll
    for (int j = 0; j < 4; ++j) {
      accL[j] = fmaf(wb, (float)hb[j], accL[j]);
      accH[j] = fmaf(wb, (float)hb[j + 4], accH[j]);
    }
  }
  if (e < m) {
    unsigned ra = pkt[start + e];
    float wa = upw(ra);
    f16x8 ha = *(const f16x8*)(hwt + (size_t)(ra >> 16) * D + sub * 8);
    #pragma unroll
    for (int j = 0; j < 4; ++j) {
      accL[j] = fmaf(wa, (float)ha[j], accL[j]);
      accH[j] = fmaf(wa, (float)ha[j + 4], accH[j]);
    }
  }
  // wave-synchronous LDS reduce across the 4 groups of each node
  float* rw = &red[wv][nd * 4 + grp][sub * 8];
  *(f32x4*)(rw) = accL;
  *(f32x4*)(rw + 4) = accH;
  __builtin_amdgcn_wave_barrier();
  // epilogue: lane owns feature `lane`, loops over the 2 nodes
  #pragma unroll
  for (int d2 = 0; d2 < 2; ++d2) {
    int nn = nA + d2;
    float s = red[wv][d2 * 4 + 0][lane] + red[wv][d2 * 4 + 1][lane] +
              red[wv][d2 * 4 + 2][lane] + red[wv][d2 * 4 + 3][lane];
    float selfv = d2 ? selfB : selfA;
    float dn = d2 ? dnB : dnA;
    float v = fmaxf(fmaf(dn, s + selfv, bi), 0.f);
    size_t ro;
    if (SCATTER) {
      int rr2 = gidx[(size_t)t * R + nn];
      ro = ((size_t)rr2 * T + t) * D + lane;
    } else {
      ro = ((size_t)t * N + nn) * D + lane;
    }
    outp[ro] = (h16)v;
  }
}

// ---------------------------------------------------------------- fused attention tail
// One block = 16 r's (160 te rows). qkv MFMA -> LDS, attention, out_proj MFMA,
// LN1, fc MFMA, LN2 -> global f32 out. kv never touches global memory.
constexpr int KVP = 132;   // kv row pad (f16) -> 264 B rows, 2-way bank spread
constexpr int P72 = 72;    // 16-row tile pad  -> 144 B rows, 16B-aligned

__global__ __launch_bounds__(256) void k_tail(
    const h16* __restrict__ te,      // [R*T][64] f16
    const h16* __restrict__ WIb,     // in_proj [192][64]
    const float* __restrict__ inB,
    const h16* __restrict__ WOb,     // out_proj [64][64]
    const float* __restrict__ outB,
    const h16* __restrict__ WFb,     // fc [64][64]
    const float* __restrict__ fcB,
    const float* __restrict__ w1,
    const float* __restrict__ w2,
    const float* __restrict__ w3,
    const float* __restrict__ w4,
    const float* __restrict__ g1, const float* __restrict__ b1,
    const float* __restrict__ g2, const float* __restrict__ b2,
    float* __restrict__ outp) {
  __shared__ __align__(16) h16 kvl[160][KVP];   // k cols 0..63, v cols 64..127
  __shared__ __align__(16) h16 ql[16][P72];
  __shared__ __align__(16) h16 aol[16][P72];
  __shared__ __align__(16) h16 tbuf[16][P72];   // proj, then o2
  __shared__ __align__(16) h16 fbuf[16][P72];   // finb
  __shared__ __align__(16) float pf[16][64];    // fin f32

  int wv = threadIdx.x >> 6, lane = threadIdx.x & 63;
  int half = lane & 15, quad = lane >> 4;
  int g0 = blockIdx.x * 160;  // first global te row (r0*T)

  // ---- step 1: qkv = te @ in_w^T (+b) into LDS
  for (int tt = wv; tt < 10; tt += 4) {
    int lr = tt * 16 + half;  // local row 0..159
    const h16* Bp = te + (size_t)(g0 + lr) * 64 + quad * 8;
    f16x8 b0 = *(const f16x8*)(Bp);
    f16x8 b1f = *(const f16x8*)(Bp + 32);
    int rloc = lr / 10;
    bool isq = (lr - rloc * 10) == 9;
    #pragma unroll
    for (int jt = 0; jt < 12; ++jt) {
      f32x4 acc = {0.f, 0.f, 0.f, 0.f};
      const h16* Wp = WIb + (size_t)(jt * 16 + half) * 64 + quad * 8;
      acc = __builtin_amdgcn_mfma_f32_16x16x32_f16(*(const f16x8*)(Wp), b0, acc, 0, 0, 0);
      acc = __builtin_amdgcn_mfma_f32_16x16x32_f16(*(const f16x8*)(Wp + 32), b1f, acc, 0, 0, 0);
      int j = jt * 16 + quad * 4;
      float4 b4 = *(const float4*)(inB + j);
      f16x4 o;
      o[0] = (h16)(acc[0] + b4.x); o[1] = (h16)(acc[1] + b4.y);
      o[2] = (h16)(acc[2] + b4.z); o[3] = (h16)(acc[3] + b4.w);
      if (jt < 4) {
        if (isq) *(f16x4*)(&ql[rloc][j]) = o;
      } else {
        *(f16x4*)(&kvl[lr][j - 64]) = o;
      }
    }
  }
  __syncthreads();

  // ---- step 2: attention (one wave per r, 4 rounds); lane = feature
  #pragma unroll
  for (int i = 0; i < 4; ++i) {
    int rl = wv * 4 + i;
    float qv = (float)ql[rl][lane];
    float sc[T], vv[T];
    #pragma unroll
    for (int s = 0; s < T; ++s) {
      float kk = (float)kvl[rl * 10 + s][lane];
      vv[s] = (float)kvl[rl * 10 + s][64 + lane];
      float p = qv * kk;
      p += __shfl_xor(p, 8, 16);
      p += __shfl_xor(p, 4, 16);
      p += __shfl_xor(p, 2, 16);
      p += __shfl_xor(p, 1, 16);
      sc[s] = p * 0.25f;  // 1/sqrt(16)
    }
    float mx = sc[0];
    #pragma unroll
    for (int s = 1; s < T; ++s) mx = fmaxf(mx, sc[s]);
    float ssum = 0.f;
    #pragma unroll
    for (int s = 0; s < T; ++s) { sc[s] = expf(sc[s] - mx); ssum += sc[s]; }
    float rinv = 1.0f / ssum;
    float aov = 0.f;
    #pragma unroll
    for (int s = 0; s < T; ++s) aov = fmaf(sc[s] * rinv, vv[s], aov);
    aol[rl][lane] = (h16)aov;
  }
  __syncthreads();

  // ---- step 3: proj = ao @ out_w^T + outB (one 16x64 tile; wave wv owns jt=wv)
  {
    const h16* Bp = &aol[half][quad * 8];
    f16x8 b0 = *(const f16x8*)(Bp);
    f16x8 b1f = *(const f16x8*)(Bp + 32);
    f32x4 acc = {0.f, 0.f, 0.f, 0.f};
    const h16* Wp = WOb + (size_t)(wv * 16 + half) * 64 + quad * 8;
    acc = __builtin_amdgcn_mfma_f32_16x16x32_f16(*(const f16x8*)(Wp), b0, acc, 0, 0, 0);
    acc = __builtin_amdgcn_mfma_f32_16x16x32_f16(*(const f16x8*)(Wp + 32), b1f, acc, 0, 0, 0);
    int j = wv * 16 + quad * 4;
    float4 b4 = *(const float4*)(outB + j);
    f16x4 o;
    o[0] = (h16)(acc[0] + b4.x); o[1] = (h16)(acc[1] + b4.y);
    o[2] = (h16)(acc[2] + b4.z); o[3] = (h16)(acc[3] + b4.w);
    *(f16x4*)(&tbuf[half][j]) = o;
  }
  __syncthreads();

  // ---- step 4: LN1 per r (one wave per r, 4 rounds)
  {
    float w1l = w1[(T - 1) * 64 + lane];
    float w2l = w2[(T - 1) * 64 + lane];
    float g1l = g1[lane], b1l = b1[lane];
    #pragma unroll
    for (int i = 0; i < 4; ++i) {
      int rl = wv * 4 + i;
      float t9 = (float)te[(size_t)(g0 + rl * 10 + 9) * 64 + lane];
      float pr = (float)tbuf[rl][lane];
      float pre = w1l * t9 + w2l * pr;
      float s1 = pre;
      #pragma unroll
      for (int off = 32; off >= 1; off >>= 1) s1 += __shfl_xor(s1, off, 64);
      float mu = s1 * (1.0f / 64.0f);
      float dv = pre - mu;
      float s2 = dv * dv;
      #pragma unroll
      for (int off = 32; off >= 1; off >>= 1) s2 += __shfl_xor(s2, off, 64);
      float rstd = 1.0f / sqrtf(s2 * (1.0f / 64.0f) + 1e-5f);
      float fin = dv * rstd * g1l + b1l;
      pf[rl][lane] = fin;
      fbuf[rl][lane] = (h16)fin;
    }
  }
  __syncthreads();

  // ---- step 5: o2 = fin @ fc_w^T + fcB
  {
    const h16* Bp = &fbuf[half][quad * 8];
    f16x8 b0 = *(const f16x8*)(Bp);
    f16x8 b1f = *(const f16x8*)(Bp + 32);
    f32x4 acc = {0.f, 0.f, 0.f, 0.f};
    const h16* Wp = WFb + (size_t)(wv * 16 + half) * 64 + quad * 8;
    acc = __builtin_amdgcn_mfma_f32_16x16x32_f16(*(const f16x8*)(Wp), b0, acc, 0, 0, 0);
    acc = __builtin_amdgcn_mfma_f32_16x16x32_f16(*(const f16x8*)(Wp + 32), b1f, acc, 0, 0, 0);
    int j = wv * 16 + quad * 4;
    float4 b4 = *(const float4*)(fcB + j);
    f16x4 o;
    o[0] = (h16)(acc[0] + b4.x); o[1] = (h16)(acc[1] + b4.y);
    o[2] = (h16)(acc[2] + b4.z); o[3] = (h16)(acc[3] + b4.w);
    *(f16x4*)(&tbuf[half][j]) = o;
  }
  __syncthreads();

  // ---- step 6: LN2 per r -> global out
  {
    float w3l = w3[lane], w4l = w4[lane];
    float g2l = g2[lane], b2l = b2[lane];
    #pragma unroll
    for (int i = 0; i < 4; ++i) {
      int rl = wv * 4 + i;
      float fin = pf[rl][lane];
      float oo = (float)tbuf[rl][lane];
      float pre = w3l * fin + w4l * oo;
      float s1 = pre;
      #pragma unroll
      for (int off = 32; off >= 1; off >>= 1) s1 += __shfl_xor(s1, off, 64);
      float mu = s1 * (1.0f / 64.0f);
      float dv = pre - mu;
      float s2 = dv * dv;
      #pragma unroll
      for (int off = 32; off >= 1; off >>= 1) s2 += __shfl_xor(s2, off, 64);
      float rstd = 1.0f / sqrtf(s2 * (1.0f / 64.0f) + 1e-5f);
      outp[(size_t)(blockIdx.x * 16 + rl) * 64 + lane] = dv * rstd * g2l + b2l;
    }
  }
}

}  // namespace

extern "C" void kernel_launch(void* const* d_in, const int* in_sizes, int n_in,
                              void* d_out, int out_size, void* d_ws, size_t ws_size,
                              hipStream_t stream) {
  const float* x      = (const float*)d_in[0];
  const int*   ei     = (const int*)d_in[1];
  const float* ew     = (const float*)d_in[2];
  const int*   gidx   = (const int*)d_in[3];
  const float* gcn1_w = (const float*)d_in[4];
  const float* gcn1_b = (const float*)d_in[5];
  const float* gcn2_w = (const float*)d_in[6];
  const float* gcn2_b = (const float*)d_in[7];
  const float* in_w   = (const float*)d_in[8];
  const float* in_b   = (const float*)d_in[9];
  const float* out_w  = (const float*)d_in[10];
  const float* out_b  = (const float*)d_in[11];
  const float* w1     = (const float*)d_in[12];
  const float* w2     = (const float*)d_in[13];
  const float* w3     = (const float*)d_in[14];
  const float* w4     = (const float*)d_in[15];
  const float* ln1_g  = (const float*)d_in[16];
  const float* ln1_b  = (const float*)d_in[17];
  const float* ln2_g  = (const float*)d_in[18];
  const float* ln2_b  = (const float*)d_in[19];
  const float* fc_w   = (const float*)d_in[20];
  const float* fc_b   = (const float*)d_in[21];
  float* outp = (float*)d_out;

  char* ws = (char*)d_ws;
  size_t off = 0;
  auto alloc = [&](size_t bytes) {
    void* p = ws + off;
    off += (bytes + 255) & ~(size_t)255;
    return p;
  };
  // persistent region
  h16* h1te = (h16*)alloc(sizeof(h16) * (size_t)T * N * D);  // h1 / time_embeds
  h16* Wb   = (h16*)alloc(sizeof(h16) * 32768);
  int* tbase = (int*)alloc(sizeof(int) * 16);
  // graph-prep buffers
  float* dinv   = (float*)alloc(sizeof(float) * T * N);
  int*   cnt    = (int*)alloc(sizeof(int) * T * N);
  int*   rowptr = (int*)alloc(sizeof(int) * T * N);
  unsigned* pk  = (unsigned*)alloc(sizeof(unsigned) * (size_t)T * E);  // 16 MB
  // union: pu (dead after k_fill2) aliased by hw (first written at GCN1 k_mm)
  size_t pu_off = off;
  unsigned* pu  = (unsigned*)alloc(sizeof(unsigned) * (size_t)T * NR * SEG * BINS);  // 65.5 MB
  h16* hw = (h16*)(ws + pu_off);
  size_t hw_end = pu_off + sizeof(h16) * (size_t)T * N * D;
  if (hw_end > off) off = hw_end;

  const h16* W1b = Wb;           // gcn1_w  [64][128]
  const h16* W2b = Wb + 8192;    // gcn2_w  [64][64]
  const h16* WIb = Wb + 12288;   // in_w    [192][64]
  const h16* WOb = Wb + 24576;   // out_w   [64][64]
  const h16* WFb = Wb + 28672;   // fc_w    [64][64]

  const int M = T * N;
  const int MW = M / 16;   // 31250
  const int PREP_BLOCKS = T * NR * SEG;  // 1000

  // weight cvt + tbase zero first (independent of edge passes)
  k_prep<<<129, 256, 0, stream>>>(gcn1_w, gcn2_w, in_w, out_w, fc_w, Wb, tbase);

  // graph prep — LDS-binned, one block-atomic per 256 nodes
  k_hist<<<PREP_BLOCKS, 256, 0, stream>>>(ei, ew, pu);
  dim3 hg((N + 255) / 256, T);
  k_hreduce2<<<hg, 256, 0, stream>>>(pu, cnt, dinv, rowptr, tbase);
  k_fill2<<<PREP_BLOCKS, 256, 0, stream>>>(ei, ew, pu, pk);

  // GCN stage (hw rows pre-scaled by dinv via MODE 2)
  dim3 gg(N / 8, T);
  k_mm<DIN, 4, false, 2><<<(MW + 3) / 4, 256, 0, stream>>>(W1b, x, dinv, hw, MW);
  k_gather<false><<<gg, 256, 0, stream>>>(hw, pk, dinv, rowptr, cnt, gcn1_b, nullptr, h1te);
  k_mm<D, 4, true, 2><<<(MW + 3) / 4, 256, 0, stream>>>(W2b, h1te, dinv, hw, MW);
  k_gather<true><<<gg, 256, 0, stream>>>(hw, pk, dinv, rowptr, cnt, gcn2_b, gidx, h1te);

  // fused attention tail: qkv + attn + out_proj + ln1 + fc + ln2
  k_tail<<<R / 16, 256, 0, stream>>>(h1te, WIb, in_b, WOb, out_b, WFb, fc_b,
                                     w1, w2, w3, w4, ln1_g, ln1_b, ln2_g, ln2_b, outp);
}